// Round 2
// baseline (251.328 us; speedup 1.0000x reference)
//
#include <hip/hip_runtime.h>
#include <hip/hip_fp16.h>

typedef _Float16 f16;
typedef f16 f16x8 __attribute__((ext_vector_type(8)));
typedef float f32x4 __attribute__((ext_vector_type(4)));

constexpr int T = 64;
constexpr int H = 4096;
constexpr int I = 11008;
constexpr int GS = 128;
constexpr int GH = 32;   // H / GS
constexpr int GI = 86;   // I / GS

// ---------------- x f32 -> f16 ----------------
__global__ __launch_bounds__(256) void k_cvt(const float* __restrict__ x,
                                             f16* __restrict__ y) {
    int i = blockIdx.x * 256 + threadIdx.x;
    y[i] = (f16)x[i];
}

// dequant 8 consecutive int32 quants -> 8 fp16 weights: w = q*s - zp*s
__device__ __forceinline__ f16x8 dq8(const int* __restrict__ qp, float sv, float zv) {
    int4 a = *(const int4*)qp;
    int4 b = *(const int4*)(qp + 4);
    f16x8 r;
    auto p0 = __builtin_amdgcn_cvt_pkrtz((float)a.x * sv - zv, (float)a.y * sv - zv);
    auto p1 = __builtin_amdgcn_cvt_pkrtz((float)a.z * sv - zv, (float)a.w * sv - zv);
    auto p2 = __builtin_amdgcn_cvt_pkrtz((float)b.x * sv - zv, (float)b.y * sv - zv);
    auto p3 = __builtin_amdgcn_cvt_pkrtz((float)b.z * sv - zv, (float)b.w * sv - zv);
    r[0] = p0[0]; r[1] = p0[1]; r[2] = p1[0]; r[3] = p1[1];
    r[4] = p2[0]; r[5] = p2[1]; r[6] = p3[0]; r[7] = p3[1];
    return r;
}

// ---------------- fused gate/up: h = silu(x@w1^T) * (x@w3^T), fp16 out ----------------
// grid: I/16 blocks, 512 threads (8 waves).
// wave w: matrix = w&1 (0->w1, 1->w3), K-quarter = w>>1. LDS-reduce + silu fuse.
__global__ __launch_bounds__(512) void k_gateup(
    const f16* __restrict__ x16,
    const int* __restrict__ q1, const float* __restrict__ s1, const int* __restrict__ zp1,
    const int* __restrict__ q3, const float* __restrict__ s3, const int* __restrict__ zp3,
    f16* __restrict__ hbuf)
{
    const int wave = threadIdx.x >> 6;
    const int lane = threadIdx.x & 63;
    const int lo = lane & 15, hi = lane >> 4;
    const int mat = wave & 1;
    const int kq = wave >> 1;         // 0..3
    const int rb = blockIdx.x * 16;
    const int row = rb + lo;          // weight row (N index)

    const int*   q  = mat ? q3 : q1;
    const float* s  = mat ? s3 : s1;
    const int*   zp = mat ? zp3 : zp1;

    const int*   qrow  = q  + (size_t)row * H;
    const float* srow  = s  + (size_t)row * GH;
    const int*   zprow = zp + (size_t)row * GH;

    f32x4 acc[4] = {};

    const int g0 = kq * (GH / 4), g1 = g0 + (GH / 4);
    for (int g = g0; g < g1; ++g) {
        float sv = srow[g];
        float zv = (float)zprow[g] * sv;
        int kb = g * GS + hi * 8;
        #pragma unroll
        for (int sub = 0; sub < 4; ++sub) {
            int k = kb + sub * 32;
            f16x8 bfrag = dq8(qrow + k, sv, zv);
            #pragma unroll
            for (int mt = 0; mt < 4; ++mt) {
                f16x8 afrag = *(const f16x8*)(x16 + (size_t)(mt * 16 + lo) * H + k);
                acc[mt] = __builtin_amdgcn_mfma_f32_16x16x32_f16(afrag, bfrag, acc[mt], 0, 0, 0);
            }
        }
    }

    // D layout: col(N) = lane&15, row(M=token) = 4*(lane>>4) + reg
    __shared__ float xs[8][T][17];
    #pragma unroll
    for (int mt = 0; mt < 4; ++mt)
        #pragma unroll
        for (int j = 0; j < 4; ++j)
            xs[wave][mt * 16 + hi * 4 + j][lo] = acc[mt][j];
    __syncthreads();

    for (int e = threadIdx.x; e < T * 16; e += 512) {
        int t = e >> 4, c = e & 15;
        float g1v = xs[0][t][c] + xs[2][t][c] + xs[4][t][c] + xs[6][t][c];
        float g3v = xs[1][t][c] + xs[3][t][c] + xs[5][t][c] + xs[7][t][c];
        float sil = g1v / (1.f + __expf(-g1v));
        hbuf[(size_t)t * I + rb + c] = (f16)(sil * g3v);
    }
}

// ---------------- down proj: part[y] = h @ w2^T (K split 16 ways: 2 grid x 8 waves) ----
// grid: (H/16, 2), 512 threads (8 waves). Wave w handles K-chunk (y*8+w) of 16.
__global__ __launch_bounds__(512) void k_down(
    const f16* __restrict__ hbuf,
    const int* __restrict__ q2, const float* __restrict__ s2, const int* __restrict__ zp2,
    float* __restrict__ part)
{
    const int wave = threadIdx.x >> 6;
    const int lane = threadIdx.x & 63;
    const int lo = lane & 15, hi = lane >> 4;
    const int rb = blockIdx.x * 16;
    const int row = rb + lo;          // weight row = output column (H)
    const int c = blockIdx.y * 8 + wave;   // 0..15
    const int g0 = (c * GI) >> 4, g1 = ((c + 1) * GI) >> 4;

    const int*   qrow  = q2  + (size_t)row * I;
    const float* srow  = s2  + (size_t)row * GI;
    const int*   zprow = zp2 + (size_t)row * GI;

    f32x4 acc[4] = {};
    for (int g = g0; g < g1; ++g) {
        float sv = srow[g];
        float zv = (float)zprow[g] * sv;
        int kb = g * GS + hi * 8;
        #pragma unroll
        for (int sub = 0; sub < 4; ++sub) {
            int k = kb + sub * 32;
            f16x8 bfrag = dq8(qrow + k, sv, zv);
            #pragma unroll
            for (int mt = 0; mt < 4; ++mt) {
                f16x8 afrag = *(const f16x8*)(hbuf + (size_t)(mt * 16 + lo) * I + k);
                acc[mt] = __builtin_amdgcn_mfma_f32_16x16x32_f16(afrag, bfrag, acc[mt], 0, 0, 0);
            }
        }
    }

    __shared__ float xs[8][T][17];
    #pragma unroll
    for (int mt = 0; mt < 4; ++mt)
        #pragma unroll
        for (int j = 0; j < 4; ++j)
            xs[wave][mt * 16 + hi * 4 + j][lo] = acc[mt][j];
    __syncthreads();

    float* p = part + (size_t)blockIdx.y * T * H;
    for (int e = threadIdx.x; e < T * 16; e += 512) {
        int t = e >> 4, cc = e & 15;
        float v = xs[0][t][cc] + xs[1][t][cc] + xs[2][t][cc] + xs[3][t][cc]
                + xs[4][t][cc] + xs[5][t][cc] + xs[6][t][cc] + xs[7][t][cc];
        p[(size_t)t * H + rb + cc] = v;
    }
}

// ---------------- reduce 2 partials -> out ----------------
__global__ __launch_bounds__(256) void k_reduce(const float* __restrict__ part,
                                                float* __restrict__ out) {
    int i = blockIdx.x * 256 + threadIdx.x;
    constexpr int N = T * H;
    out[i] = part[i] + part[N + i];
}

extern "C" void kernel_launch(void* const* d_in, const int* in_sizes, int n_in,
                              void* d_out, int out_size, void* d_ws, size_t ws_size,
                              hipStream_t stream) {
    const float* x   = (const float*)d_in[0];
    const int*   q1  = (const int*)d_in[1];
    const float* s1  = (const float*)d_in[2];
    const int*   zp1 = (const int*)d_in[3];
    const int*   q3  = (const int*)d_in[4];
    const float* s3  = (const float*)d_in[5];
    const int*   zp3 = (const int*)d_in[6];
    const int*   q2  = (const int*)d_in[7];
    const float* s2  = (const float*)d_in[8];
    const int*   zp2 = (const int*)d_in[9];

    char* ws = (char*)d_ws;
    f16*   x16  = (f16*)ws;                              // 524288 B
    f16*   hbuf = (f16*)(ws + 524288);                   // 1409024 B
    float* part = (float*)(ws + 524288 + 1409024);       // 2097152 B

    k_cvt<<<T * H / 256, 256, 0, stream>>>(x, x16);
    k_gateup<<<I / 16, 512, 0, stream>>>(x16, q1, s1, zp1, q3, s3, zp3, hbuf);
    k_down<<<dim3(H / 16, 2), 512, 0, stream>>>(hbuf, q2, s2, zp2, part);
    k_reduce<<<T * H / 256, 256, 0, stream>>>(part, (float*)d_out);
}

// Round 3
// 171.767 us; speedup vs baseline: 1.4632x; 1.4632x over previous
//
#include <hip/hip_runtime.h>
#include <hip/hip_fp16.h>

typedef _Float16 f16;
typedef f16 f16x8 __attribute__((ext_vector_type(8)));
typedef float f32x4 __attribute__((ext_vector_type(4)));

constexpr int T = 64;
constexpr int H = 4096;
constexpr int I = 11008;
constexpr int GH = 32;   // H/128
constexpr int GI = 86;   // I/128

// async global->LDS, 16B per lane. lds ptr must be wave-uniform (HW adds lane*16).
__device__ __forceinline__ void gll16(const void* g, void* l) {
    __builtin_amdgcn_global_load_lds(
        (const __attribute__((address_space(1))) unsigned int*)g,
        (__attribute__((address_space(3))) unsigned int*)l, 16, 0, 0);
}

// dequant 8 int32 (two int4 halves) -> 8 f16:  w = q*s - zp*s
__device__ __forceinline__ f16x8 dq8v(int4 a, int4 b, float sv, float zv) {
    f16x8 r;
    auto p0 = __builtin_amdgcn_cvt_pkrtz((float)a.x * sv - zv, (float)a.y * sv - zv);
    auto p1 = __builtin_amdgcn_cvt_pkrtz((float)a.z * sv - zv, (float)a.w * sv - zv);
    auto p2 = __builtin_amdgcn_cvt_pkrtz((float)b.x * sv - zv, (float)b.y * sv - zv);
    auto p3 = __builtin_amdgcn_cvt_pkrtz((float)b.z * sv - zv, (float)b.w * sv - zv);
    r[0] = p0[0]; r[1] = p0[1]; r[2] = p1[0]; r[3] = p1[1];
    r[4] = p2[0]; r[5] = p2[1]; r[6] = p3[0]; r[7] = p3[1];
    return r;
}

// x [64][4096] f32 -> tiled f16 xp[w:128][m:64][hi:4][8]: A-frag loads become 1KB-contiguous
__global__ __launch_bounds__(256) void k_cvt(const float* __restrict__ x,
                                             f16* __restrict__ xp) {
    int C = blockIdx.x * 256 + threadIdx.x;        // 0..32767
    int w = C >> 8, m = (C >> 2) & 63, hi = C & 3;
    const float* src = x + (size_t)m * H + w * 32 + hi * 8;
    float4 a = *(const float4*)src;
    float4 b = *(const float4*)(src + 4);
    f16x8 o;
    o[0] = (f16)a.x; o[1] = (f16)a.y; o[2] = (f16)a.z; o[3] = (f16)a.w;
    o[4] = (f16)b.x; o[5] = (f16)b.y; o[6] = (f16)b.z; o[7] = (f16)b.w;
    *(f16x8*)(xp + (size_t)C * 8) = o;
}

// ---------- gate/up partial GEMM: part[ks*2+mat][T][I] = x @ w^T (K-quarter ks) ----------
// grid (172, 4), 512 thr = 8 waves = 2 mat x 4 nsub. N=64 rows/block, K=8 groups/block.
__global__ __launch_bounds__(512, 4) void k_gateup(
    const f16* __restrict__ xp,
    const int* __restrict__ q1, const float* __restrict__ s1, const int* __restrict__ zp1,
    const int* __restrict__ q3, const float* __restrict__ s3, const int* __restrict__ zp3,
    float* __restrict__ part)
{
    __shared__ int tile[2 * 8192];                 // 2 matrices x 64 rows x 128 int32
    const int t = threadIdx.x;
    const int wv = t >> 6, lane = t & 63, lo = lane & 15, hi = lane >> 4;
    const int mat = wv & 1, nsub = wv >> 1;
    const int R0 = blockIdx.x * 64;
    const int ks = blockIdx.y;                     // K quarter
    const int brow = nsub * 16 + lo;               // row within tile
    const int grow = R0 + brow;                    // global weight row
    const float* sm = mat ? s3 : s1;
    const int*   zm = mat ? zp3 : zp1;

    f32x4 acc[4] = {};

    for (int gl = 0; gl < 8; ++gl) {
        int g = ks * 8 + gl;
        float sv = sm[(size_t)grow * GH + g];
        float zv = (float)zm[(size_t)grow * GH + g] * sv;

        __syncthreads();                           // prev tile fully consumed
        #pragma unroll
        for (int k4 = 0; k4 < 4; ++k4) {
            int P = t + k4 * 512;                  // 16B-granule index in tile
            int row = P >> 5, c = P & 31, cs = c ^ (row & 7);   // source pre-swizzle
            size_t gb = (size_t)(R0 + row) * (H * 4) + (size_t)g * 512 + cs * 16;
            int ldsi = (wv * 64 + k4 * 512) * 4;   // wave-uniform int index
            gll16((const char*)q1 + gb, (void*)&tile[ldsi]);
            gll16((const char*)q3 + gb, (void*)&tile[8192 + ldsi]);
        }
        asm volatile("s_waitcnt vmcnt(0)" ::: "memory");
        __syncthreads();                           // staged tile visible

        #pragma unroll
        for (int w = 0; w < 4; ++w) {
            int cc = (w * 8 + hi * 2) ^ (brow & 7);            // read-side swizzle
            int byte0 = mat * 32768 + (brow * 32 + cc) * 16;
            int4 b0 = *(const int4*)((const char*)tile + byte0);
            int4 b1 = *(const int4*)((const char*)tile + (byte0 ^ 16));
            f16x8 bf = dq8v(b0, b1, sv, zv);
            int wg = g * 4 + w;
            #pragma unroll
            for (int mt = 0; mt < 4; ++mt) {
                f16x8 af = *(const f16x8*)(xp + ((size_t)wg * 256 + (mt * 16 + lo) * 4 + hi) * 8);
                acc[mt] = __builtin_amdgcn_mfma_f32_16x16x32_f16(af, bf, acc[mt], 0, 0, 0);
            }
        }
    }

    float* pb = part + (size_t)(ks * 2 + mat) * T * I;
    #pragma unroll
    for (int mt = 0; mt < 4; ++mt)
        #pragma unroll
        for (int j = 0; j < 4; ++j)
            pb[(size_t)(mt * 16 + hi * 4 + j) * I + R0 + brow] = acc[mt][j];
}

// ---------- combine: h = silu(gate)*up, write tiled hp[w:344][m:64][hi:4][8] f16 ----------
__global__ __launch_bounds__(256) void k_comb(const float* __restrict__ part,
                                              f16* __restrict__ hp) {
    int C = blockIdx.x * 256 + threadIdx.x;        // 0..88063
    int w = C >> 8, m = (C >> 2) & 63, hi = C & 3;
    int col = w * 32 + hi * 8;
    float ga[8] = {}, ua[8] = {};
    #pragma unroll
    for (int ks = 0; ks < 4; ++ks) {
        const float* pg = part + ((size_t)(ks * 2 + 0) * T + m) * I + col;
        const float* pu = part + ((size_t)(ks * 2 + 1) * T + m) * I + col;
        float4 g0 = *(const float4*)pg, g1 = *(const float4*)(pg + 4);
        float4 u0 = *(const float4*)pu, u1 = *(const float4*)(pu + 4);
        ga[0] += g0.x; ga[1] += g0.y; ga[2] += g0.z; ga[3] += g0.w;
        ga[4] += g1.x; ga[5] += g1.y; ga[6] += g1.z; ga[7] += g1.w;
        ua[0] += u0.x; ua[1] += u0.y; ua[2] += u0.z; ua[3] += u0.w;
        ua[4] += u1.x; ua[5] += u1.y; ua[6] += u1.z; ua[7] += u1.w;
    }
    f16x8 o;
    #pragma unroll
    for (int j = 0; j < 8; ++j) {
        float gv = ga[j];
        o[j] = (f16)(gv / (1.f + __expf(-gv)) * ua[j]);
    }
    *(f16x8*)(hp + (size_t)C * 8) = o;
}

// ---------- down partial GEMM: part2[y][T][H], grid (64, 8), 8 waves = 4 nsub x 2 kh ----
__global__ __launch_bounds__(512, 4) void k_down(
    const f16* __restrict__ hp,
    const int* __restrict__ q2, const float* __restrict__ s2, const int* __restrict__ zp2,
    float* __restrict__ part2)
{
    __shared__ int tile[8192];                     // 64 rows x 128 int32
    __shared__ float xs[4][64][17];
    const int t = threadIdx.x;
    const int wv = t >> 6, lane = t & 63, lo = lane & 15, hi = lane >> 4;
    const int nsub = wv & 3, kh = wv >> 2;
    const int R0 = blockIdx.x * 64;
    const int y = blockIdx.y;
    const int g0 = (y * GI) >> 3, g1 = ((y + 1) * GI) >> 3;
    const int brow = nsub * 16 + lo;
    const int grow = R0 + brow;

    f32x4 acc[4] = {};

    for (int g = g0; g < g1; ++g) {
        float sv = s2[(size_t)grow * GI + g];
        float zv = (float)zp2[(size_t)grow * GI + g] * sv;

        __syncthreads();
        #pragma unroll
        for (int k4 = 0; k4 < 4; ++k4) {
            int P = t + k4 * 512;
            int row = P >> 5, c = P & 31, cs = c ^ (row & 7);
            size_t gb = (size_t)(R0 + row) * ((size_t)I * 4) + (size_t)g * 512 + cs * 16;
            gll16((const char*)q2 + gb, (void*)&tile[(wv * 64 + k4 * 512) * 4]);
        }
        asm volatile("s_waitcnt vmcnt(0)" ::: "memory");
        __syncthreads();

        #pragma unroll
        for (int ww = 0; ww < 2; ++ww) {
            int w = kh * 2 + ww;
            int cc = (w * 8 + hi * 2) ^ (brow & 7);
            int byte0 = (brow * 32 + cc) * 16;
            int4 b0 = *(const int4*)((const char*)tile + byte0);
            int4 b1 = *(const int4*)((const char*)tile + (byte0 ^ 16));
            f16x8 bf = dq8v(b0, b1, sv, zv);
            int wg = g * 4 + w;
            #pragma unroll
            for (int mt = 0; mt < 4; ++mt) {
                f16x8 af = *(const f16x8*)(hp + ((size_t)wg * 256 + (mt * 16 + lo) * 4 + hi) * 8);
                acc[mt] = __builtin_amdgcn_mfma_f32_16x16x32_f16(af, bf, acc[mt], 0, 0, 0);
            }
        }
    }

    __syncthreads();
    if (kh == 1) {
        #pragma unroll
        for (int mt = 0; mt < 4; ++mt)
            #pragma unroll
            for (int j = 0; j < 4; ++j)
                xs[nsub][mt * 16 + hi * 4 + j][lo] = acc[mt][j];
    }
    __syncthreads();
    if (kh == 0) {
        float* pb = part2 + (size_t)y * T * H;
        #pragma unroll
        for (int mt = 0; mt < 4; ++mt)
            #pragma unroll
            for (int j = 0; j < 4; ++j) {
                int m = mt * 16 + hi * 4 + j;
                pb[(size_t)m * H + R0 + brow] = acc[mt][j] + xs[nsub][m][lo];
            }
    }
}

// ---------- reduce 8 down-partials -> out f32 ----------
__global__ __launch_bounds__(256) void k_red(const float* __restrict__ part2,
                                             float* __restrict__ out) {
    int i = (blockIdx.x * 256 + threadIdx.x) * 4;
    float4 s = {0.f, 0.f, 0.f, 0.f};
    #pragma unroll
    for (int y = 0; y < 8; ++y) {
        float4 v = *(const float4*)(part2 + (size_t)y * T * H + i);
        s.x += v.x; s.y += v.y; s.z += v.z; s.w += v.w;
    }
    *(float4*)(out + i) = s;
}

extern "C" void kernel_launch(void* const* d_in, const int* in_sizes, int n_in,
                              void* d_out, int out_size, void* d_ws, size_t ws_size,
                              hipStream_t stream) {
    const float* x   = (const float*)d_in[0];
    const int*   q1  = (const int*)d_in[1];
    const float* s1  = (const float*)d_in[2];
    const int*   zp1 = (const int*)d_in[3];
    const int*   q3  = (const int*)d_in[4];
    const float* s3  = (const float*)d_in[5];
    const int*   zp3 = (const int*)d_in[6];
    const int*   q2  = (const int*)d_in[7];
    const float* s2  = (const float*)d_in[8];
    const int*   zp2 = (const int*)d_in[9];

    char* ws = (char*)d_ws;
    f16*   xp    = (f16*)ws;                               // 524288 B
    f16*   hp    = (f16*)(ws + 524288);                    // 1409024 B
    float* part  = (float*)(ws + 524288 + 1409024);        // 22544384 B
    float* part2 = (float*)(ws + 524288 + 1409024 + 22544384);  // 8388608 B

    k_cvt<<<128, 256, 0, stream>>>(x, xp);
    k_gateup<<<dim3(172, 4), 512, 0, stream>>>(xp, q1, s1, zp1, q3, s3, zp3, part);
    k_comb<<<344, 256, 0, stream>>>(part, hp);
    k_down<<<dim3(64, 8), 512, 0, stream>>>(hp, q2, s2, zp2, part2);
    k_red<<<256, 256, 0, stream>>>(part2, (float*)d_out);
}